// Round 14
// baseline (158.336 us; speedup 1.0000x reference)
//
#include <hip/hip_runtime.h>
#include <hip/hip_fp16.h>

// VQEmbedding straight-through forward, fp16-MFMA 16x16x32, code-split waves:
// wave w computes ALL 64 px (A in 128 VGPR) x codes [w*16,w*16+16) per tile.
// B-tile reads per block per kt: 32 (was 128) -> LDS port (the measured
// dominant pipe, ~41us) cut 4x. launch_bounds(256,2) -> 256-VGPR budget,
// no spill (r10 lesson). Cross-wave top-4 merge in LDS (exact: global top-4
// is the top-4 of the union of per-wave top-4s).
//   z_e_x: [B=64, C=256, H=32, W=32] fp32, codebook: [K=1024, C=256] fp32
//   out: (z_q_x, z_q_x) both [B,C,H,W] fp32, concatenated flat.
//
// argmin_k ||x-c_k||^2 == argmin_k (||c_k||^2 + 256 - 2 x.c_k)  (uniform bias)
// Keys: fp32 distance bits truncated at 10 low bits | 10-bit code index.
// fp16 input-rounding + truncation absorbed by EPS=0.22 (passed r4-r13).
//   gap14 < EPS -> full fp32 rescan   (rare)
//   gap13 < EPS -> 3-candidate exact  (rare)
//   gap12 < EPS -> 2-candidate exact  (~10k px)

#define C_DIM 256
#define HW    1024
#define K_CODES 1024
#define OUT_OFF 16777216   // 64*256*32*32
#define EPS 0.22f

typedef _Float16 f16;
typedef _Float16 f16x8 __attribute__((ext_vector_type(8)));
typedef float    f32x4 __attribute__((ext_vector_type(4)));

// ws layout (bytes, 16B aligned) — identical footprint to rounds 4-13 (proven):
//   cnorm  f32[1024]       0        4096   (biased +256)
//   cnts   int[4]          4096     16     ([0]=pair+triple, [1]=rescan)
//   arena  int[65536]      4112     262144 (pairs bottom-up, rescans top-down)
//   idxarr int[65536]      266256   262144 (triple px: bits 20-29 = 3rd cand)
//   cb16f  f16[1024*256]   528400   524288 (16x16 MFMA-fragment order)
#define WS_CNORM 0
#define WS_CNTS  4096
#define WS_ARENA 4112
#define WS_IDX   266256
#define WS_CB16  528400
#define WS_NEED  1052688u

__device__ __forceinline__ unsigned umn(unsigned a, unsigned b) { return a < b ? a : b; }
__device__ __forceinline__ unsigned umx(unsigned a, unsigned b) { return a > b ? a : b; }

// sorted-insert x into ascending quad (a1..a4)
__device__ __forceinline__ void ins4(unsigned& a1, unsigned& a2, unsigned& a3,
                                     unsigned& a4, unsigned x) {
    unsigned u1 = umx(a1, x);  a1 = umn(a1, x);
    unsigned u2 = umx(a2, u1); a2 = umn(a2, u1);
    unsigned u3 = umx(a3, u2); a3 = umn(a3, u2);
    a4 = umn(a4, u3);
}

__device__ __forceinline__ void gl16(const void* g, void* l) {
    __builtin_amdgcn_global_load_lds(
        (const __attribute__((address_space(1))) unsigned int*)g,
        (__attribute__((address_space(3))) unsigned int*)l, 16, 0, 0);
}

// ---- fused prep: blocks [0,128) -> cb16f (16x16 fragment order);
// blocks [128,384) -> cnorm (+256 bias); block 128 zeroes counters.
// cb16f slot s = ((kt*4 + ct)*8 + kk)*64 + l holds 8 f16:
//   element j: cb[kt*64 + ct*16 + (l&15)][kk*32 + (l>>4)*8 + j]
__global__ __launch_bounds__(256) void vq_prep_kernel(const float* __restrict__ cb,
                                                      float* __restrict__ cnorm,
                                                      f16* __restrict__ cb16f,
                                                      int* __restrict__ cnts) {
    const int bid = blockIdx.x;
    const int t   = threadIdx.x;
    if (bid < 128) {
        int s  = bid * 256 + t;          // 0..32767
        int l  = s & 63;
        int kk = (s >> 6) & 7;
        int ct = (s >> 9) & 3;
        int kt = s >> 11;
        int code = kt * 64 + ct * 16 + (l & 15);
        int k0   = kk * 32 + (l >> 4) * 8;
        const float* row = cb + (size_t)code * C_DIM + k0;
        float4 a = *reinterpret_cast<const float4*>(row);
        float4 b = *reinterpret_cast<const float4*>(row + 4);
        f16x8 h;
        h[0] = (f16)a.x; h[1] = (f16)a.y; h[2] = (f16)a.z; h[3] = (f16)a.w;
        h[4] = (f16)b.x; h[5] = (f16)b.y; h[6] = (f16)b.z; h[7] = (f16)b.w;
        *reinterpret_cast<f16x8*>(&cb16f[(size_t)s * 8]) = h;
    } else {
        if (bid == 128 && t < 4) cnts[t] = 0;
        const int lane = t & 63;
        const int k    = (bid - 128) * 4 + (t >> 6);
        float4 v = *reinterpret_cast<const float4*>(&cb[(size_t)k * C_DIM + 4 * lane]);
        float s = v.x * v.x + v.y * v.y + v.z * v.z + v.w * v.w;
#pragma unroll
        for (int m = 1; m < 64; m <<= 1) s += __shfl_xor(s, m, 64);
        if (lane == 0) cnorm[k] = s + 256.f;
    }
}

// ---- main kernel: block = 64 px x 1024 codes; grid 1024; 4 waves, wave w
// owns codes ct=w of each 64-code tile, all 64 px in registers (af[4][8]).
__global__ __launch_bounds__(256, 2) void vq_mfma_kernel(const float* __restrict__ z,
                                                         const f16* __restrict__ cb16f,
                                                         const float* __restrict__ cnorm,
                                                         int* __restrict__ cnts,
                                                         int* __restrict__ arena,
                                                         int* __restrict__ idxarr) {
    __shared__ __align__(16) union {
        f16      cs[16384];       // 32 KB: 64 codes x 256 d, fragment order
        float    xs[4160];        // 16.6 KB: 64 ch x 64 px (stride 65), prologue
        unsigned sk[4][64][4];    // 4 KB: cross-wave top-4 merge (post-loop)
    } L;
    __shared__ float cns[K_CODES];   // 4 KB

    const int t    = threadIdx.x;
    const int bid  = blockIdx.x;
    const int b    = bid >> 4;
    const int hw0  = (bid & 15) << 6;
    const size_t zbase = (size_t)b * (C_DIM * HW) + hw0;

    const int lane = t & 63;
    const int w    = t >> 6;      // wave id == its code quarter (ct)
    const int l15  = lane & 15;
    const int l4   = lane >> 4;

#pragma unroll
    for (int r = 0; r < 4; ++r) cns[t + 256 * r] = cnorm[t + 256 * r];

    // ---- A prologue: 4 chunks of 64 channels x 64 px via LDS transpose.
    // af[atile][cc*2+kkl]: px = atile*16 + l15, k = cc*64 + kkl*32 + l4*8 + j.
    f16x8 af[4][8];
#pragma unroll
    for (int cc = 0; cc < 4; ++cc) {
        __syncthreads();
#pragma unroll
        for (int i = 0; i < 4; ++i) {
            int id  = t + 256 * i;          // 0..1023
            int c   = id >> 4;              // 0..63
            int px4 = (id & 15) << 2;       // 0..60
            float4 v = *reinterpret_cast<const float4*>(
                &z[zbase + (size_t)(cc * 64 + c) * HW + px4]);
            float* xr = &L.xs[c * 65 + px4];
            xr[0] = v.x; xr[1] = v.y; xr[2] = v.z; xr[3] = v.w;
        }
        __syncthreads();
#pragma unroll
        for (int kkl = 0; kkl < 2; ++kkl) {
#pragma unroll
            for (int atile = 0; atile < 4; ++atile) {
                int px    = atile * 16 + l15;
                int cbase = kkl * 32 + l4 * 8;
                f16x8 h;
#pragma unroll
                for (int j = 0; j < 8; ++j)
                    h[j] = (f16)L.xs[(cbase + j) * 65 + px];
                af[atile][cc * 2 + kkl] = h;
            }
        }
    }

    unsigned k1[16], k2[16], k3[16], k4[16];   // slot s = atile*4 + reg
#pragma unroll
    for (int s = 0; s < 16; ++s) { k1[s] = k2[s] = k3[s] = k4[s] = 0xFFFFFFFFu; }

    for (int kt = 0; kt < 16; ++kt) {
        __syncthreads();   // prior tile's readers done (covers prologue on kt=0)
        const f16* src = cb16f + (size_t)kt * 16384;
#pragma unroll
        for (int r = 0; r < 8; ++r) {
            int slot = r * 256 + t;
            gl16(src + (size_t)slot * 8, &L.cs[slot * 8]);
        }
        __syncthreads();   // vmcnt drain: tile ready

        f32x4 acc[4];
#pragma unroll
        for (int a = 0; a < 4; ++a) acc[a] = (f32x4)0.f;

        // wave reads ONLY its code quarter: 8 ds_reads/kt, 32 MFMA/kt.
#pragma unroll
        for (int kk = 0; kk < 8; ++kk) {
            f16x8 bf = *reinterpret_cast<const f16x8*>(&L.cs[((w * 8 + kk) * 64 + lane) * 8]);
            acc[0] = __builtin_amdgcn_mfma_f32_16x16x32_f16(af[0][kk], bf, acc[0], 0, 0, 0);
            acc[1] = __builtin_amdgcn_mfma_f32_16x16x32_f16(af[1][kk], bf, acc[1], 0, 0, 0);
            acc[2] = __builtin_amdgcn_mfma_f32_16x16x32_f16(af[2][kk], bf, acc[2], 0, 0, 0);
            acc[3] = __builtin_amdgcn_mfma_f32_16x16x32_f16(af[3][kk], bf, acc[3], 0, 0, 0);
        }

        // keys: d = cnorm+256 - 2 x.c ; truncate low 10 bits | code index.
        // D layout: row(px in atile) = l4*4 + reg, col(code) = l15.
        const int code  = kt * 64 + w * 16 + l15;
        const float cnv = cns[code];
#pragma unroll
        for (int a = 0; a < 4; ++a) {
#pragma unroll
            for (int reg = 0; reg < 4; ++reg) {
                float d = fmaf(-2.f, acc[a][reg], cnv);
                unsigned key = (__float_as_uint(d) & 0xFFFFFC00u) | (unsigned)code;
                int s = a * 4 + reg;
                ins4(k1[s], k2[s], k3[s], k4[s], key);
            }
        }
    }

    // ---- reduce top-4 across the 16 code-lanes; publish per wave to LDS.
    __syncthreads();   // cs reads done; safe to overlay sk
#pragma unroll
    for (int s = 0; s < 16; ++s) {
        unsigned a1 = k1[s], a2 = k2[s], a3 = k3[s], a4 = k4[s];
#pragma unroll
        for (int m = 1; m < 16; m <<= 1) {
            unsigned b1 = __shfl_xor(a1, m, 16);
            unsigned b2 = __shfl_xor(a2, m, 16);
            unsigned b3 = __shfl_xor(a3, m, 16);
            unsigned b4 = __shfl_xor(a4, m, 16);
            ins4(a1, a2, a3, a4, b1);
            ins4(a1, a2, a3, a4, b2);
            ins4(a1, a2, a3, a4, b3);
            ins4(a1, a2, a3, a4, b4);
        }
        if (l15 == 0) {
            int px = (s >> 2) * 16 + (l4 << 2) + (s & 3);   // atile*16 + l4*4 + reg
            L.sk[w][px][0] = a1;
            L.sk[w][px][1] = a2;
            L.sk[w][px][2] = a3;
            L.sk[w][px][3] = a4;
        }
    }
    __syncthreads();

    // ---- merge 4 waves' candidates (exact global top-4); classify; write.
    if (t < 64) {
        unsigned a1 = L.sk[0][t][0], a2 = L.sk[0][t][1];
        unsigned a3 = L.sk[0][t][2], a4 = L.sk[0][t][3];
#pragma unroll
        for (int wv = 1; wv < 4; ++wv) {
            ins4(a1, a2, a3, a4, L.sk[wv][t][0]);
            ins4(a1, a2, a3, a4, L.sk[wv][t][1]);
            ins4(a1, a2, a3, a4, L.sk[wv][t][2]);
            ins4(a1, a2, a3, a4, L.sk[wv][t][3]);
        }
        int gp = (bid << 6) + t;
        float v1 = __uint_as_float(a1 & 0xFFFFFC00u);
        float v2 = __uint_as_float(a2 & 0xFFFFFC00u);
        float v3 = __uint_as_float(a3 & 0xFFFFFC00u);
        float v4 = __uint_as_float(a4 & 0xFFFFFC00u);
        int i1 = (int)(a1 & 1023u);
        int i2 = (int)(a2 & 1023u);
        int i3 = (int)(a3 & 1023u);
        int iv = i1;
        if (v4 - v1 < EPS) {                 // >=4 candidates: full rescan
            int p = atomicAdd(&cnts[1], 1);
            arena[65535 - p] = gp;
        } else if (v3 - v1 < EPS) {          // 3 candidates
            int p = atomicAdd(&cnts[0], 1);
            arena[p] = gp | (i2 << 16) | (int)0x80000000u;
            iv = i1 | (i3 << 20);
        } else if (v2 - v1 < EPS) {          // 2 candidates
            int p = atomicAdd(&cnts[0], 1);
            arena[p] = gp | (i2 << 16);
        }
        idxarr[gp] = iv;
    }
}

// ---- fused refine+rescan: blocks [0,1024) pair/triple compares (wave each);
// blocks [1024,1536) full fp32 rescans (block per px).
__global__ __launch_bounds__(256) void vq_refine_kernel(const float* __restrict__ z,
                                                        const float* __restrict__ cb,
                                                        const float* __restrict__ cnorm,
                                                        const int* __restrict__ cnts,
                                                        const int* __restrict__ arena,
                                                        int* __restrict__ idxarr) {
    const int t = threadIdx.x;
    if (blockIdx.x < 1024) {
        const int lane = t & 63;
        const int wid  = (blockIdx.x * 256 + t) >> 6;
        const int nw   = 1024 * 4;
        const int nb   = cnts[0];
        for (int i = wid; i < nb; i += nw) {
            int e  = arena[i];
            int gp = e & 0xFFFF;
            int j2 = (e >> 16) & 1023;
            bool tri = e < 0;
            int iv = idxarr[gp];
            int c1 = iv & 1023;
            int j3 = (iv >> 20) & 1023;
            int b = gp >> 10, hw = gp & 1023;
            const float* xb = z + (size_t)b * (C_DIM * HW) + hw;
            float x0 = xb[(size_t)(4 * lane + 0) * HW];
            float x1 = xb[(size_t)(4 * lane + 1) * HW];
            float x2 = xb[(size_t)(4 * lane + 2) * HW];
            float x3 = xb[(size_t)(4 * lane + 3) * HW];
            float4 r1 = *reinterpret_cast<const float4*>(&cb[(size_t)c1 * C_DIM + 4 * lane]);
            float4 r2 = *reinterpret_cast<const float4*>(&cb[(size_t)j2 * C_DIM + 4 * lane]);
            float s1 = fmaf(x0, r1.x, fmaf(x1, r1.y, fmaf(x2, r1.z, x3 * r1.w)));
            float s2 = fmaf(x0, r2.x, fmaf(x1, r2.y, fmaf(x2, r2.z, x3 * r2.w)));
            float s3 = 0.f;
            if (tri) {
                float4 r3 = *reinterpret_cast<const float4*>(&cb[(size_t)j3 * C_DIM + 4 * lane]);
                s3 = fmaf(x0, r3.x, fmaf(x1, r3.y, fmaf(x2, r3.z, x3 * r3.w)));
            }
#pragma unroll
            for (int m = 1; m < 64; m <<= 1) {
                s1 += __shfl_xor(s1, m, 64);
                s2 += __shfl_xor(s2, m, 64);
                s3 += __shfl_xor(s3, m, 64);
            }
            if (lane == 0) {
                float d1 = fmaf(-2.f, s1, cnorm[c1]);
                float d2 = fmaf(-2.f, s2, cnorm[j2]);
                int bi = c1; float bd = d1;
                if (d2 < bd || (d2 == bd && j2 < bi)) { bd = d2; bi = j2; }
                if (tri) {
                    float d3 = fmaf(-2.f, s3, cnorm[j3]);
                    if (d3 < bd || (d3 == bd && j3 < bi)) { bd = d3; bi = j3; }
                }
                idxarr[gp] = bi;
            }
        }
    } else {
        __shared__ float xw[C_DIM];
        __shared__ float rdv[4];
        __shared__ int   rdi[4];
        const int nr = cnts[1];
        for (int q = blockIdx.x - 1024; q < nr; q += 512) {
            int gp = arena[65535 - q];
            int b = gp >> 10, hw = gp & 1023;
            __syncthreads();
            xw[t] = z[(size_t)b * (C_DIM * HW) + (size_t)t * HW + hw];
            __syncthreads();
            float bd = 3.4e38f; int bi = 0;
#pragma unroll
            for (int rr = 0; rr < 4; ++rr) {
                int k = rr * 256 + t;   // ascending -> strict < keeps lowest
                const float4* cr = reinterpret_cast<const float4*>(cb + (size_t)k * C_DIM);
                float s0 = 0.f, s1 = 0.f, s2 = 0.f, s3 = 0.f;
#pragma unroll 8
                for (int d4 = 0; d4 < 64; ++d4) {
                    float4 cv = cr[d4];
                    s0 = fmaf(xw[4 * d4 + 0], cv.x, s0);
                    s1 = fmaf(xw[4 * d4 + 1], cv.y, s1);
                    s2 = fmaf(xw[4 * d4 + 2], cv.z, s2);
                    s3 = fmaf(xw[4 * d4 + 3], cv.w, s3);
                }
                float dist = fmaf(-2.f, (s0 + s1) + (s2 + s3), cnorm[k]);
                if (dist < bd) { bd = dist; bi = k; }
            }
#pragma unroll
            for (int m = 1; m < 64; m <<= 1) {
                float od = __shfl_xor(bd, m, 64);
                int   oi = __shfl_xor(bi, m, 64);
                if (od < bd || (od == bd && oi < bi)) { bd = od; bi = oi; }
            }
            if ((t & 63) == 0) { rdv[t >> 6] = bd; rdi[t >> 6] = bi; }
            __syncthreads();
            if (t == 0) {
                float fb = rdv[0]; int fi = rdi[0];
#pragma unroll
                for (int u = 1; u < 4; ++u) {
                    if (rdv[u] < fb || (rdv[u] == fb && rdi[u] < fi)) { fb = rdv[u]; fi = rdi[u]; }
                }
                idxarr[gp] = fi;
            }
            __syncthreads();
        }
    }
}

// ---- gather: 64 px per block, grid 1024 (4 blocks/CU) for write-BW.
__global__ __launch_bounds__(256) void vq_gather_kernel(const float* __restrict__ cb,
                                                        const int* __restrict__ idxarr,
                                                        float* __restrict__ out) {
    __shared__ int idxs[64];
    const int t = threadIdx.x;
    if (t < 64) idxs[t] = idxarr[blockIdx.x * 64 + t] & 1023;
    __syncthreads();
    const int b     = blockIdx.x >> 4;
    const int hw0   = (blockIdx.x & 15) << 6;
    const int px4   = (t & 15) << 2;
    const int cbase = t >> 4;               // 0..15
    const float* r0 = cb + (size_t)idxs[px4 + 0] * C_DIM;
    const float* r1 = cb + (size_t)idxs[px4 + 1] * C_DIM;
    const float* r2 = cb + (size_t)idxs[px4 + 2] * C_DIM;
    const float* r3 = cb + (size_t)idxs[px4 + 3] * C_DIM;
    const size_t obase = (size_t)b * (C_DIM * HW) + hw0 + px4;
#pragma unroll
    for (int i = 0; i < 16; ++i) {
        int c = cbase + 16 * i;
        float4 v = { r0[c], r1[c], r2[c], r3[c] };
        *reinterpret_cast<float4*>(&out[obase + (size_t)c * HW]) = v;
        *reinterpret_cast<float4*>(&out[obase + (size_t)c * HW + OUT_OFF]) = v;
    }
}

// ---------------- fallback (round-1 exact fp32 kernels, needs only 4KB ws) ----
__global__ __launch_bounds__(256) void vq_cnorm_kernel(const float* __restrict__ cb,
                                                       float* __restrict__ cnorm) {
    int k = blockIdx.x * 256 + threadIdx.x;
    if (k >= K_CODES) return;
    const float4* row = reinterpret_cast<const float4*>(cb + (size_t)k * C_DIM);
    float s = 0.f;
#pragma unroll 8
    for (int u = 0; u < C_DIM / 4; ++u) {
        float4 v = row[u];
        s += v.x * v.x + v.y * v.y + v.z * v.z + v.w * v.w;
    }
    cnorm[k] = s;
}

__global__ __launch_bounds__(256, 4) void vq_main_kernel(const float* __restrict__ z,
                                                         const float* __restrict__ cb,
                                                         const float* __restrict__ cnorm,
                                                         float* __restrict__ out) {
    __shared__ float Xs[64][64];
    __shared__ float Bs[64][68];
    __shared__ float cns[K_CODES];
    __shared__ int   idxs[64];

    const int t  = threadIdx.x;
    const int tx = t & 15;
    const int ty = t >> 4;
    const int b   = blockIdx.x >> 4;
    const int hw0 = (blockIdx.x & 15) << 6;
    const size_t zbase = (size_t)b * (C_DIM * HW) + hw0;

#pragma unroll
    for (int r = 0; r < 4; ++r) cns[t + 256 * r] = cnorm[t + 256 * r];

    float best[4];
    int   bidx[4];
#pragma unroll
    for (int i = 0; i < 4; ++i) { best[i] = 3.4e38f; bidx[i] = 0; }

    for (int kt = 0; kt < 16; ++kt) {
        float acc[4][4];
#pragma unroll
        for (int i = 0; i < 4; ++i)
#pragma unroll
            for (int j = 0; j < 4; ++j) acc[i][j] = 0.f;

        for (int cc = 0; cc < 4; ++cc) {
            const int c0g = cc * 64;
            __syncthreads();
#pragma unroll
            for (int r = 0; r < 4; ++r) {
                int c   = (t >> 4) + 16 * r;
                int px4 = (t & 15) * 4;
                *reinterpret_cast<float4*>(&Xs[c][px4]) =
                    *reinterpret_cast<const float4*>(&z[zbase + (size_t)(c0g + c) * HW + px4]);
                int k  = (t >> 4) + 16 * r;
                int c4 = (t & 15) * 4;
                *reinterpret_cast<float4*>(&Bs[k][c4]) =
                    *reinterpret_cast<const float4*>(&cb[(size_t)(kt * 64 + k) * C_DIM + c0g + c4]);
            }
            __syncthreads();

#pragma unroll
            for (int c0 = 0; c0 < 64; c0 += 4) {
                float4 xv[4], bv[4];
#pragma unroll
                for (int s = 0; s < 4; ++s)
                    xv[s] = *reinterpret_cast<const float4*>(&Xs[c0 + s][4 * ty]);
#pragma unroll
                for (int j = 0; j < 4; ++j)
                    bv[j] = *reinterpret_cast<const float4*>(&Bs[16 * j + tx][c0]);
#pragma unroll
                for (int i = 0; i < 4; ++i) {
#pragma unroll
                    for (int j = 0; j < 4; ++j) {
                        float xi0 = (i == 0) ? xv[0].x : (i == 1) ? xv[0].y : (i == 2) ? xv[0].z : xv[0].w;
                        float xi1 = (i == 0) ? xv[1].x : (i == 1) ? xv[1].y : (i == 2) ? xv[1].z : xv[1].w;
                        float xi2 = (i == 0) ? xv[2].x : (i == 1) ? xv[2].y : (i == 2) ? xv[2].z : xv[2].w;
                        float xi3 = (i == 0) ? xv[3].x : (i == 1) ? xv[3].y : (i == 2) ? xv[3].z : xv[3].w;
                        acc[i][j] = fmaf(xi0, bv[j].x,
                                    fmaf(xi1, bv[j].y,
                                    fmaf(xi2, bv[j].z,
                                    fmaf(xi3, bv[j].w, acc[i][j]))));
                    }
                }
            }
        }

#pragma unroll
        for (int j = 0; j < 4; ++j) {
            int kg = kt * 64 + 16 * j + tx;
            float cnv = cns[kg];
#pragma unroll
            for (int i = 0; i < 4; ++i) {
                float d = cnv - 2.f * acc[i][j];
                if (d < best[i]) { best[i] = d; bidx[i] = kg; }
            }
        }
    }

#pragma unroll
    for (int i = 0; i < 4; ++i) {
#pragma unroll
        for (int off = 8; off >= 1; off >>= 1) {
            float od = __shfl_xor(best[i], off, 16);
            int   oi = __shfl_xor(bidx[i], off, 16);
            if (od < best[i] || (od == best[i] && oi < bidx[i])) { best[i] = od; bidx[i] = oi; }
        }
        if (tx == 0) idxs[4 * ty + i] = bidx[i];
    }
    __syncthreads();

    const int px = t & 63;
    const int c0 = t >> 6;
    const int code = idxs[px];
    const float* crow = cb + (size_t)code * C_DIM;
    const size_t obase = (size_t)b * (C_DIM * HW) + hw0 + px;
#pragma unroll 4
    for (int c = c0; c < C_DIM; c += 4) {
        float v = crow[c];
        out[obase + (size_t)c * HW] = v;
        out[obase + (size_t)c * HW + OUT_OFF] = v;
    }
}

extern "C" void kernel_launch(void* const* d_in, const int* in_sizes, int n_in,
                              void* d_out, int out_size, void* d_ws, size_t ws_size,
                              hipStream_t stream) {
    const float* z  = (const float*)d_in[0];
    const float* cb = (const float*)d_in[1];
    float* out = (float*)d_out;

    float* cnorm  = (float*)((char*)d_ws + WS_CNORM);
    int*   cnts   = (int*)((char*)d_ws + WS_CNTS);
    int*   arena  = (int*)((char*)d_ws + WS_ARENA);
    int*   idxarr = (int*)((char*)d_ws + WS_IDX);
    f16*   cb16f  = (f16*)((char*)d_ws + WS_CB16);

    if (ws_size >= WS_NEED) {
        vq_prep_kernel<<<384, 256, 0, stream>>>(cb, cnorm, cb16f, cnts);
        vq_mfma_kernel<<<1024, 256, 0, stream>>>(z, cb16f, cnorm, cnts, arena, idxarr);
        vq_refine_kernel<<<1536, 256, 0, stream>>>(z, cb, cnorm, cnts, arena, idxarr);
        vq_gather_kernel<<<1024, 256, 0, stream>>>(cb, idxarr, out);
    } else {
        vq_cnorm_kernel<<<K_CODES / 256, 256, 0, stream>>>(cb, cnorm);
        vq_main_kernel<<<1024, 256, 0, stream>>>(z, cb, cnorm, out);
    }
}

// Round 15
// 143.667 us; speedup vs baseline: 1.1021x; 1.1021x over previous
//
#include <hip/hip_runtime.h>
#include <hip/hip_fp16.h>

// VQEmbedding straight-through forward, fp16-MFMA 16x16x32, 2x2 wave split
// (wave = 32 px x 32 codes: B-tile LDS reads halved vs r13) with TOP-3 keys
// to fit the 128-VGPR cap of launch_bounds(256,4) -> 4 blocks/CU (the
// occupancy law established by r9/r11/r13/r14). gap13<EPS -> full rescan.
//   z_e_x: [B=64, C=256, H=32, W=32] fp32, codebook: [K=1024, C=256] fp32
//   out: (z_q_x, z_q_x) both [B,C,H,W] fp32, concatenated flat.
//
// argmin_k ||x-c_k||^2 == argmin_k (||c_k||^2 + 256 - 2 x.c_k)  (uniform bias)
// Keys: fp32 distance bits truncated at 10 low bits | 10-bit code index.
// fp16 input-rounding + truncation absorbed by EPS=0.22 (passed r4-r14).
//   gap13 < EPS -> full fp32 rescan   (~600 px)
//   gap12 < EPS -> 2-candidate exact  (~9k px)
//   else        -> winner exact.

#define C_DIM 256
#define HW    1024
#define K_CODES 1024
#define OUT_OFF 16777216   // 64*256*32*32
#define EPS 0.22f

typedef _Float16 f16;
typedef _Float16 f16x8 __attribute__((ext_vector_type(8)));
typedef float    f32x4 __attribute__((ext_vector_type(4)));

// ws layout (bytes, 16B aligned) — identical footprint to rounds 4-14 (proven):
//   cnorm  f32[1024]       0        4096   (biased +256)
//   cnts   int[4]          4096     16     ([0]=pairs, [1]=rescans)
//   arena  int[65536]      4112     262144 (pairs bottom-up, rescans top-down)
//   idxarr int[65536]      266256   262144
//   cb16f  f16[1024*256]   528400   524288 (16x16 MFMA-fragment order)
#define WS_CNORM 0
#define WS_CNTS  4096
#define WS_ARENA 4112
#define WS_IDX   266256
#define WS_CB16  528400
#define WS_NEED  1052688u

__device__ __forceinline__ unsigned umn(unsigned a, unsigned b) { return a < b ? a : b; }
__device__ __forceinline__ unsigned umx(unsigned a, unsigned b) { return a > b ? a : b; }

// sorted-insert x into ascending triple (a1..a3): 5 ops
__device__ __forceinline__ void ins3(unsigned& a1, unsigned& a2, unsigned& a3,
                                     unsigned x) {
    unsigned u1 = umx(a1, x);  a1 = umn(a1, x);
    unsigned u2 = umx(a2, u1); a2 = umn(a2, u1);
    a3 = umn(a3, u2);
}

__device__ __forceinline__ void gl16(const void* g, void* l) {
    __builtin_amdgcn_global_load_lds(
        (const __attribute__((address_space(1))) unsigned int*)g,
        (__attribute__((address_space(3))) unsigned int*)l, 16, 0, 0);
}

// ---- fused prep: blocks [0,128) -> cb16f (16x16 fragment order);
// blocks [128,384) -> cnorm (+256 bias); block 128 zeroes counters.
// cb16f slot s = ((kt*4 + ct)*8 + kk)*64 + l holds 8 f16:
//   element j: cb[kt*64 + ct*16 + (l&15)][kk*32 + (l>>4)*8 + j]
__global__ __launch_bounds__(256) void vq_prep_kernel(const float* __restrict__ cb,
                                                      float* __restrict__ cnorm,
                                                      f16* __restrict__ cb16f,
                                                      int* __restrict__ cnts) {
    const int bid = blockIdx.x;
    const int t   = threadIdx.x;
    if (bid < 128) {
        int s  = bid * 256 + t;          // 0..32767
        int l  = s & 63;
        int kk = (s >> 6) & 7;
        int ct = (s >> 9) & 3;
        int kt = s >> 11;
        int code = kt * 64 + ct * 16 + (l & 15);
        int k0   = kk * 32 + (l >> 4) * 8;
        const float* row = cb + (size_t)code * C_DIM + k0;
        float4 a = *reinterpret_cast<const float4*>(row);
        float4 b = *reinterpret_cast<const float4*>(row + 4);
        f16x8 h;
        h[0] = (f16)a.x; h[1] = (f16)a.y; h[2] = (f16)a.z; h[3] = (f16)a.w;
        h[4] = (f16)b.x; h[5] = (f16)b.y; h[6] = (f16)b.z; h[7] = (f16)b.w;
        *reinterpret_cast<f16x8*>(&cb16f[(size_t)s * 8]) = h;
    } else {
        if (bid == 128 && t < 4) cnts[t] = 0;
        const int lane = t & 63;
        const int k    = (bid - 128) * 4 + (t >> 6);
        float4 v = *reinterpret_cast<const float4*>(&cb[(size_t)k * C_DIM + 4 * lane]);
        float s = v.x * v.x + v.y * v.y + v.z * v.z + v.w * v.w;
#pragma unroll
        for (int m = 1; m < 64; m <<= 1) s += __shfl_xor(s, m, 64);
        if (lane == 0) cnorm[k] = s + 256.f;
    }
}

// ---- main kernel: block = 64 px x 1024 codes; grid 1024; 4 waves in 2x2:
// wm = px half (32 px), wn = code half (32 codes of each 64-code tile).
// Each B fragment read once per wave feeds 2 MFMA (B-reads halved vs r13).
__global__ __launch_bounds__(256, 4) void vq_mfma_kernel(const float* __restrict__ z,
                                                         const f16* __restrict__ cb16f,
                                                         const float* __restrict__ cnorm,
                                                         int* __restrict__ cnts,
                                                         int* __restrict__ arena,
                                                         int* __restrict__ idxarr) {
    __shared__ __align__(16) union {
        f16      cs[16384];      // 32 KB: 64 codes x 256 d, fragment order
        float    xs[4160];       // 16.6 KB: 64 ch x 64 px (stride 65), prologue
        unsigned sk[3][2][64];   // 1.5 KB: cross-half top-3 merge (post-loop)
    } L;
    __shared__ float cns[K_CODES];   // 4 KB

    const int t    = threadIdx.x;
    const int bid  = blockIdx.x;
    const int b    = bid >> 4;
    const int hw0  = (bid & 15) << 6;
    const size_t zbase = (size_t)b * (C_DIM * HW) + hw0;

    const int lane = t & 63;
    const int w    = t >> 6;
    const int wm   = w >> 1;      // px half
    const int wn   = w & 1;       // code half
    const int l15  = lane & 15;
    const int l4   = lane >> 4;

#pragma unroll
    for (int r = 0; r < 4; ++r) cns[t + 256 * r] = cnorm[t + 256 * r];

    // ---- A prologue: 4 chunks of 64 channels x 64 px via LDS transpose.
    // af[tile][cc*2+kkl]: px = wm*32 + tile*16 + l15, k = cc*64+kkl*32+l4*8+j
    // (cbase is chunk-LOCAL — the r12 bug was adding cc*64 here.)
    f16x8 af[2][8];
#pragma unroll
    for (int cc = 0; cc < 4; ++cc) {
        __syncthreads();
#pragma unroll
        for (int i = 0; i < 4; ++i) {
            int id  = t + 256 * i;          // 0..1023
            int c   = id >> 4;              // 0..63
            int px4 = (id & 15) << 2;       // 0..60
            float4 v = *reinterpret_cast<const float4*>(
                &z[zbase + (size_t)(cc * 64 + c) * HW + px4]);
            float* xr = &L.xs[c * 65 + px4];
            xr[0] = v.x; xr[1] = v.y; xr[2] = v.z; xr[3] = v.w;
        }
        __syncthreads();
#pragma unroll
        for (int kkl = 0; kkl < 2; ++kkl) {
#pragma unroll
            for (int tile = 0; tile < 2; ++tile) {
                int px    = wm * 32 + tile * 16 + l15;
                int cbase = kkl * 32 + l4 * 8;
                f16x8 h;
#pragma unroll
                for (int j = 0; j < 8; ++j)
                    h[j] = (f16)L.xs[(cbase + j) * 65 + px];
                af[tile][cc * 2 + kkl] = h;
            }
        }
    }

    unsigned k1[8], k2[8], k3[8];   // slot s = tile*4 + reg
#pragma unroll
    for (int s = 0; s < 8; ++s) { k1[s] = k2[s] = k3[s] = 0xFFFFFFFFu; }

    for (int kt = 0; kt < 16; ++kt) {
        __syncthreads();   // prior tile's readers done (covers prologue on kt=0)
        const f16* src = cb16f + (size_t)kt * 16384;
#pragma unroll
        for (int r = 0; r < 8; ++r) {
            int slot = r * 256 + t;
            gl16(src + (size_t)slot * 8, &L.cs[slot * 8]);
        }
        __syncthreads();   // vmcnt drain: tile ready

        f32x4 acc[2][2];
#pragma unroll
        for (int i = 0; i < 2; ++i)
#pragma unroll
            for (int j = 0; j < 2; ++j) acc[i][j] = (f32x4)0.f;

        // wave reads only its code half: 16 ds_reads/kt, each feeds 2 MFMA.
#pragma unroll
        for (int kk = 0; kk < 8; ++kk) {
            f16x8 b0 = *reinterpret_cast<const f16x8*>(&L.cs[(((2 * wn + 0) * 8 + kk) * 64 + lane) * 8]);
            f16x8 b1 = *reinterpret_cast<const f16x8*>(&L.cs[(((2 * wn + 1) * 8 + kk) * 64 + lane) * 8]);
            acc[0][0] = __builtin_amdgcn_mfma_f32_16x16x32_f16(af[0][kk], b0, acc[0][0], 0, 0, 0);
            acc[0][1] = __builtin_amdgcn_mfma_f32_16x16x32_f16(af[0][kk], b1, acc[0][1], 0, 0, 0);
            acc[1][0] = __builtin_amdgcn_mfma_f32_16x16x32_f16(af[1][kk], b0, acc[1][0], 0, 0, 0);
            acc[1][1] = __builtin_amdgcn_mfma_f32_16x16x32_f16(af[1][kk], b1, acc[1][1], 0, 0, 0);
        }

        // keys: d = cnorm+256 - 2 x.c ; truncate low 10 bits | code index.
        // D layout: row(px in 16-tile) = l4*4 + reg, col(code) = l15.
        const int ktbase = kt * 64;
#pragma unroll
        for (int cj = 0; cj < 2; ++cj) {
            int code  = ktbase + (2 * wn + cj) * 16 + l15;
            float cnv = cns[code];
#pragma unroll
            for (int tile = 0; tile < 2; ++tile) {
#pragma unroll
                for (int reg = 0; reg < 4; ++reg) {
                    float d = fmaf(-2.f, acc[tile][cj][reg], cnv);
                    unsigned key = (__float_as_uint(d) & 0xFFFFFC00u) | (unsigned)code;
                    int s = tile * 4 + reg;
                    ins3(k1[s], k2[s], k3[s], key);
                }
            }
        }
    }

    // ---- reduce top-3 across the 16 code-lanes; publish per-half to LDS.
    __syncthreads();   // cs reads done; safe to overlay sk
#pragma unroll
    for (int s = 0; s < 8; ++s) {
        unsigned a1 = k1[s], a2 = k2[s], a3 = k3[s];
#pragma unroll
        for (int m = 1; m < 16; m <<= 1) {
            unsigned b1 = __shfl_xor(a1, m, 16);
            unsigned b2 = __shfl_xor(a2, m, 16);
            unsigned b3 = __shfl_xor(a3, m, 16);
            ins3(a1, a2, a3, b1);
            ins3(a1, a2, a3, b2);
            ins3(a1, a2, a3, b3);
        }
        if (l15 == 0) {
            int px = wm * 32 + (s >> 2) * 16 + (l4 << 2) + (s & 3);
            L.sk[0][wn][px] = a1;
            L.sk[1][wn][px] = a2;
            L.sk[2][wn][px] = a3;
        }
    }
    __syncthreads();

    // ---- merge the two code halves (exact top-3 of union); classify; write.
    if (t < 64) {
        unsigned a1 = L.sk[0][0][t], a2 = L.sk[1][0][t], a3 = L.sk[2][0][t];
        ins3(a1, a2, a3, L.sk[0][1][t]);
        ins3(a1, a2, a3, L.sk[1][1][t]);
        ins3(a1, a2, a3, L.sk[2][1][t]);
        int gp = (bid << 6) + t;
        float v1 = __uint_as_float(a1 & 0xFFFFFC00u);
        float v2 = __uint_as_float(a2 & 0xFFFFFC00u);
        float v3 = __uint_as_float(a3 & 0xFFFFFC00u);
        int i1 = (int)(a1 & 1023u);
        int i2 = (int)(a2 & 1023u);
        idxarr[gp] = i1;
        if (v3 - v1 < EPS) {                 // >=3 candidates: full rescan
            int p = atomicAdd(&cnts[1], 1);
            arena[65535 - p] = gp;
        } else if (v2 - v1 < EPS) {          // exactly 2 candidates: pair
            int p = atomicAdd(&cnts[0], 1);
            arena[p] = gp | (i2 << 16);
        }
    }
}

// ---- fused refine+rescan: blocks [0,1024) pair compares (wave each);
// blocks [1024,1536) full fp32 rescans (block per px).
__global__ __launch_bounds__(256) void vq_refine_kernel(const float* __restrict__ z,
                                                        const float* __restrict__ cb,
                                                        const float* __restrict__ cnorm,
                                                        const int* __restrict__ cnts,
                                                        const int* __restrict__ arena,
                                                        int* __restrict__ idxarr) {
    const int t = threadIdx.x;
    if (blockIdx.x < 1024) {
        const int lane = t & 63;
        const int wid  = (blockIdx.x * 256 + t) >> 6;
        const int nw   = 1024 * 4;
        const int nb   = cnts[0];
        for (int i = wid; i < nb; i += nw) {
            int e  = arena[i];
            int gp = e & 0xFFFF;
            int j2 = (e >> 16) & 1023;
            int c1 = idxarr[gp] & 1023;
            int b = gp >> 10, hw = gp & 1023;
            const float* xb = z + (size_t)b * (C_DIM * HW) + hw;
            float x0 = xb[(size_t)(4 * lane + 0) * HW];
            float x1 = xb[(size_t)(4 * lane + 1) * HW];
            float x2 = xb[(size_t)(4 * lane + 2) * HW];
            float x3 = xb[(size_t)(4 * lane + 3) * HW];
            float4 r1 = *reinterpret_cast<const float4*>(&cb[(size_t)c1 * C_DIM + 4 * lane]);
            float4 r2 = *reinterpret_cast<const float4*>(&cb[(size_t)j2 * C_DIM + 4 * lane]);
            float s1 = fmaf(x0, r1.x, fmaf(x1, r1.y, fmaf(x2, r1.z, x3 * r1.w)));
            float s2 = fmaf(x0, r2.x, fmaf(x1, r2.y, fmaf(x2, r2.z, x3 * r2.w)));
#pragma unroll
            for (int m = 1; m < 64; m <<= 1) {
                s1 += __shfl_xor(s1, m, 64);
                s2 += __shfl_xor(s2, m, 64);
            }
            if (lane == 0) {
                float d1 = fmaf(-2.f, s1, cnorm[c1]);
                float d2 = fmaf(-2.f, s2, cnorm[j2]);
                if (d2 < d1 || (d2 == d1 && j2 < c1)) idxarr[gp] = j2;
            }
        }
    } else {
        __shared__ float xw[C_DIM];
        __shared__ float rdv[4];
        __shared__ int   rdi[4];
        const int nr = cnts[1];
        for (int q = blockIdx.x - 1024; q < nr; q += 512) {
            int gp = arena[65535 - q];
            int b = gp >> 10, hw = gp & 1023;
            __syncthreads();
            xw[t] = z[(size_t)b * (C_DIM * HW) + (size_t)t * HW + hw];
            __syncthreads();
            float bd = 3.4e38f; int bi = 0;
#pragma unroll
            for (int rr = 0; rr < 4; ++rr) {
                int k = rr * 256 + t;   // ascending -> strict < keeps lowest
                const float4* cr = reinterpret_cast<const float4*>(cb + (size_t)k * C_DIM);
                float s0 = 0.f, s1 = 0.f, s2 = 0.f, s3 = 0.f;
#pragma unroll 8
                for (int d4 = 0; d4 < 64; ++d4) {
                    float4 cv = cr[d4];
                    s0 = fmaf(xw[4 * d4 + 0], cv.x, s0);
                    s1 = fmaf(xw[4 * d4 + 1], cv.y, s1);
                    s2 = fmaf(xw[4 * d4 + 2], cv.z, s2);
                    s3 = fmaf(xw[4 * d4 + 3], cv.w, s3);
                }
                float dist = fmaf(-2.f, (s0 + s1) + (s2 + s3), cnorm[k]);
                if (dist < bd) { bd = dist; bi = k; }
            }
#pragma unroll
            for (int m = 1; m < 64; m <<= 1) {
                float od = __shfl_xor(bd, m, 64);
                int   oi = __shfl_xor(bi, m, 64);
                if (od < bd || (od == bd && oi < bi)) { bd = od; bi = oi; }
            }
            if ((t & 63) == 0) { rdv[t >> 6] = bd; rdi[t >> 6] = bi; }
            __syncthreads();
            if (t == 0) {
                float fb = rdv[0]; int fi = rdi[0];
#pragma unroll
                for (int u = 1; u < 4; ++u) {
                    if (rdv[u] < fb || (rdv[u] == fb && rdi[u] < fi)) { fb = rdv[u]; fi = rdi[u]; }
                }
                idxarr[gp] = fi;
            }
            __syncthreads();
        }
    }
}

// ---- gather: 64 px per block, grid 1024 (4 blocks/CU) for write-BW.
__global__ __launch_bounds__(256) void vq_gather_kernel(const float* __restrict__ cb,
                                                        const int* __restrict__ idxarr,
                                                        float* __restrict__ out) {
    __shared__ int idxs[64];
    const int t = threadIdx.x;
    if (t < 64) idxs[t] = idxarr[blockIdx.x * 64 + t] & 1023;
    __syncthreads();
    const int b     = blockIdx.x >> 4;
    const int hw0   = (blockIdx.x & 15) << 6;
    const int px4   = (t & 15) << 2;
    const int cbase = t >> 4;               // 0..15
    const float* r0 = cb + (size_t)idxs[px4 + 0] * C_DIM;
    const float* r1 = cb + (size_t)idxs[px4 + 1] * C_DIM;
    const float* r2 = cb + (size_t)idxs[px4 + 2] * C_DIM;
    const float* r3 = cb + (size_t)idxs[px4 + 3] * C_DIM;
    const size_t obase = (size_t)b * (C_DIM * HW) + hw0 + px4;
#pragma unroll
    for (int i = 0; i < 16; ++i) {
        int c = cbase + 16 * i;
        float4 v = { r0[c], r1[c], r2[c], r3[c] };
        *reinterpret_cast<float4*>(&out[obase + (size_t)c * HW]) = v;
        *reinterpret_cast<float4*>(&out[obase + (size_t)c * HW + OUT_OFF]) = v;
    }
}

// ---------------- fallback (round-1 exact fp32 kernels, needs only 4KB ws) ----
__global__ __launch_bounds__(256) void vq_cnorm_kernel(const float* __restrict__ cb,
                                                       float* __restrict__ cnorm) {
    int k = blockIdx.x * 256 + threadIdx.x;
    if (k >= K_CODES) return;
    const float4* row = reinterpret_cast<const float4*>(cb + (size_t)k * C_DIM);
    float s = 0.f;
#pragma unroll 8
    for (int u = 0; u < C_DIM / 4; ++u) {
        float4 v = row[u];
        s += v.x * v.x + v.y * v.y + v.z * v.z + v.w * v.w;
    }
    cnorm[k] = s;
}

__global__ __launch_bounds__(256, 4) void vq_main_kernel(const float* __restrict__ z,
                                                         const float* __restrict__ cb,
                                                         const float* __restrict__ cnorm,
                                                         float* __restrict__ out) {
    __shared__ float Xs[64][64];
    __shared__ float Bs[64][68];
    __shared__ float cns[K_CODES];
    __shared__ int   idxs[64];

    const int t  = threadIdx.x;
    const int tx = t & 15;
    const int ty = t >> 4;
    const int b   = blockIdx.x >> 4;
    const int hw0 = (blockIdx.x & 15) << 6;
    const size_t zbase = (size_t)b * (C_DIM * HW) + hw0;

#pragma unroll
    for (int r = 0; r < 4; ++r) cns[t + 256 * r] = cnorm[t + 256 * r];

    float best[4];
    int   bidx[4];
#pragma unroll
    for (int i = 0; i < 4; ++i) { best[i] = 3.4e38f; bidx[i] = 0; }

    for (int kt = 0; kt < 16; ++kt) {
        float acc[4][4];
#pragma unroll
        for (int i = 0; i < 4; ++i)
#pragma unroll
            for (int j = 0; j < 4; ++j) acc[i][j] = 0.f;

        for (int cc = 0; cc < 4; ++cc) {
            const int c0g = cc * 64;
            __syncthreads();
#pragma unroll
            for (int r = 0; r < 4; ++r) {
                int c   = (t >> 4) + 16 * r;
                int px4 = (t & 15) * 4;
                *reinterpret_cast<float4*>(&Xs[c][px4]) =
                    *reinterpret_cast<const float4*>(&z[zbase + (size_t)(c0g + c) * HW + px4]);
                int k  = (t >> 4) + 16 * r;
                int c4 = (t & 15) * 4;
                *reinterpret_cast<float4*>(&Bs[k][c4]) =
                    *reinterpret_cast<const float4*>(&cb[(size_t)(kt * 64 + k) * C_DIM + c0g + c4]);
            }
            __syncthreads();

#pragma unroll
            for (int c0 = 0; c0 < 64; c0 += 4) {
                float4 xv[4], bv[4];
#pragma unroll
                for (int s = 0; s < 4; ++s)
                    xv[s] = *reinterpret_cast<const float4*>(&Xs[c0 + s][4 * ty]);
#pragma unroll
                for (int j = 0; j < 4; ++j)
                    bv[j] = *reinterpret_cast<const float4*>(&Bs[16 * j + tx][c0]);
#pragma unroll
                for (int i = 0; i < 4; ++i) {
#pragma unroll
                    for (int j = 0; j < 4; ++j) {
                        float xi0 = (i == 0) ? xv[0].x : (i == 1) ? xv[0].y : (i == 2) ? xv[0].z : xv[0].w;
                        float xi1 = (i == 0) ? xv[1].x : (i == 1) ? xv[1].y : (i == 2) ? xv[1].z : xv[1].w;
                        float xi2 = (i == 0) ? xv[2].x : (i == 1) ? xv[2].y : (i == 2) ? xv[2].z : xv[2].w;
                        float xi3 = (i == 0) ? xv[3].x : (i == 1) ? xv[3].y : (i == 2) ? xv[3].z : xv[3].w;
                        acc[i][j] = fmaf(xi0, bv[j].x,
                                    fmaf(xi1, bv[j].y,
                                    fmaf(xi2, bv[j].z,
                                    fmaf(xi3, bv[j].w, acc[i][j]))));
                    }
                }
            }
        }

#pragma unroll
        for (int j = 0; j < 4; ++j) {
            int kg = kt * 64 + 16 * j + tx;
            float cnv = cns[kg];
#pragma unroll
            for (int i = 0; i < 4; ++i) {
                float d = cnv - 2.f * acc[i][j];
                if (d < best[i]) { best[i] = d; bidx[i] = kg; }
            }
        }
    }

#pragma unroll
    for (int i = 0; i < 4; ++i) {
#pragma unroll
        for (int off = 8; off >= 1; off >>= 1) {
            float od = __shfl_xor(best[i], off, 16);
            int   oi = __shfl_xor(bidx[i], off, 16);
            if (od < best[i] || (od == best[i] && oi < bidx[i])) { best[i] = od; bidx[i] = oi; }
        }
        if (tx == 0) idxs[4 * ty + i] = bidx[i];
    }
    __syncthreads();

    const int px = t & 63;
    const int c0 = t >> 6;
    const int code = idxs[px];
    const float* crow = cb + (size_t)code * C_DIM;
    const size_t obase = (size_t)b * (C_DIM * HW) + hw0 + px;
#pragma unroll 4
    for (int c = c0; c < C_DIM; c += 4) {
        float v = crow[c];
        out[obase + (size_t)c * HW] = v;
        out[obase + (size_t)c * HW + OUT_OFF] = v;
    }
}

extern "C" void kernel_launch(void* const* d_in, const int* in_sizes, int n_in,
                              void* d_out, int out_size, void* d_ws, size_t ws_size,
                              hipStream_t stream) {
    const float* z  = (const float*)d_in[0];
    const float* cb = (const float*)d_in[1];
    float* out = (float*)d_out;

    float* cnorm  = (float*)((char*)d_ws + WS_CNORM);
    int*   cnts   = (int*)((char*)d_ws + WS_CNTS);
    int*   arena  = (int*)((char*)d_ws + WS_ARENA);
    int*   idxarr = (int*)((char*)d_ws + WS_IDX);
    f16*   cb16f  = (f16*)((char*)d_ws + WS_CB16);

    if (ws_size >= WS_NEED) {
        vq_prep_kernel<<<384, 256, 0, stream>>>(cb, cnorm, cb16f, cnts);
        vq_mfma_kernel<<<1024, 256, 0, stream>>>(z, cb16f, cnorm, cnts, arena, idxarr);
        vq_refine_kernel<<<1536, 256, 0, stream>>>(z, cb, cnorm, cnts, arena, idxarr);
        vq_gather_kernel<<<1024, 256, 0, stream>>>(cb, idxarr, out);
    } else {
        vq_cnorm_kernel<<<K_CODES / 256, 256, 0, stream>>>(cb, cnorm);
        vq_main_kernel<<<1024, 256, 0, stream>>>(z, cb, cnorm, out);
    }
}